// Round 12
// baseline (249.854 us; speedup 1.0000x reference)
//
#include <hip/hip_runtime.h>

typedef unsigned short u16;
typedef unsigned int   u32;
typedef __attribute__((ext_vector_type(8))) short short8;   // 8 bf16 = 4 VGPRs
typedef __attribute__((ext_vector_type(4))) float floatx4;

#define DEV static __device__ __forceinline__

constexpr int S_  = 1024;   // sequence
constexpr int Dm  = 1024;   // d_model
constexpr int HD  = 64;     // head dim
constexpr float LOG2E = 1.44269504088896f;

// ---- helpers -------------------------------------------------------------

DEV u16 f2b(float f) {            // fp32 -> bf16, round-to-nearest-even
  u32 u = __builtin_bit_cast(u32, f);
  u = u + 0x7fffu + ((u >> 16) & 1u);
  return (u16)(u >> 16);
}
DEV float b2f(u16 h) { u32 u = ((u32)h) << 16; return __builtin_bit_cast(float, u); }

DEV void gld16(const u16* g, u16* l) {   // async global->LDS, 16B per lane
  __builtin_amdgcn_global_load_lds(
      (const __attribute__((address_space(1))) u32*)g,
      (__attribute__((address_space(3))) u32*)l, 16, 0, 0);
}

// Stage ROWS x 64 bf16 tile into LDS with XOR swizzle (16B block (m,kb) at
// m*8 + (kb ^ (m&7))) so ds_read_b128 fragment reads are 2-way (free, m136).
template<int ROWS, int NT>
DEV void stage_tile(const u16* src, long stride, long kOff, u16* lds, int tid) {
  constexpr int NBLK = ROWS * 8;
  constexpr int NISS = NBLK / NT;
  static_assert(NBLK % NT == 0, "");
  int w = tid >> 6;
  #pragma unroll
  for (int i = 0; i < NISS; ++i) {
    int bi = i * NT + tid;
    int m  = bi >> 3;
    int kb = (bi & 7) ^ (m & 7);
    const u16* g = src + (long)m * stride + kOff + (kb << 3);
    u16* l = lds + ((long)(i * NT + (w << 6)) << 3);   // wave-uniform chunk base
    gld16(g, l);
  }
}

// A/B fragment read: row = lane&15, kb = ks*4 + (lane>>4)
DEV short8 read_frag(const u16* lds, int m, int kb) {
  int off = (m << 6) + ((kb ^ (m & 7)) << 3);
  return *(const short8*)(lds + off);
}

DEV floatx4 mfma16(short8 a, short8 b, floatx4 c) {
  return __builtin_amdgcn_mfma_f32_16x16x32_bf16(a, b, c, 0, 0, 0);
}

// ---- fused fp32 -> bf16 convert (y, x, Wq, Wk, Wv, Wo) -------------------

struct CvtArgs { const float* s[6]; u16* d[6]; };

__global__ __launch_bounds__(256)
void cvt_all(CvtArgs a) {
  int b = blockIdx.x;
  int t, lb;
  if (b < 4096)      { t = 0; lb = b; }
  else if (b < 8192) { t = 1; lb = b - 4096; }
  else               { t = 2 + ((b - 8192) >> 10); lb = (b - 8192) & 1023; }
  int i = (lb * 256 + (int)threadIdx.x) * 4;
  float4 v = *(const float4*)(a.s[t] + i);
  u32 lo = (u32)f2b(v.x) | ((u32)f2b(v.y) << 16);
  u32 hi = (u32)f2b(v.z) | ((u32)f2b(v.w) << 16);
  uint2 o; o.x = lo; o.y = hi;
  *(uint2*)(a.d[t] + i) = o;
}

// ---- emask prep ----------------------------------------------------------
// em[q][k] = exp(mask[q][k]) bf16 row-major (probs epilogue).
// emr4[q4][c2][r][g][j][ii] = mask*log2e bf16 where q=q4*16+g*4+r,
// k=c2*128+ii*16+j.  In attn_stats one load instruction (fixed mi,r,kt)
// reads a CONTIGUOUS 1 KB block across 64 lanes (16 lines, 100% utilized).

__global__ __launch_bounds__(256)
void emask_prep(const float* __restrict__ mask, u16* __restrict__ em,
                u16* __restrict__ emr4) {
  __shared__ u16 lp[16384];
  int tid = threadIdx.x;
  int q4 = blockIdx.x;                   // 64 blocks, 16 q-rows each
  #pragma unroll
  for (int rr = 0; rr < 16; ++rr) {
    long q = (long)q4 * 16 + rr;
    float4 v = *(const float4*)(mask + q * 1024 + tid * 4);
    u16 e0 = f2b(__expf(v.x)), e1 = f2b(__expf(v.y));
    u16 e2 = f2b(__expf(v.z)), e3 = f2b(__expf(v.w));
    uint2 o; o.x = (u32)e0 | ((u32)e1 << 16); o.y = (u32)e2 | ((u32)e3 << 16);
    *(uint2*)(em + q * 1024 + tid * 4) = o;
    int r = rr & 3, g = rr >> 2;
    float mv[4] = {v.x, v.y, v.z, v.w};
    #pragma unroll
    for (int j4 = 0; j4 < 4; ++j4) {
      int k = tid * 4 + j4;
      int c2 = k >> 7, ii = (k >> 4) & 7, j = k & 15;
      lp[((c2 * 4 + r) * 4 + g) * 128 + j * 8 + ii] = f2b(mv[j4] * LOG2E);
    }
  }
  __syncthreads();
  #pragma unroll
  for (int i = 0; i < 8; ++i) {
    int o = i * 2048 + tid * 8;
    *(uint4*)(emr4 + (long)q4 * 16384 + o) = *(const uint4*)(lp + o);
  }
}

// ---- fused Q/K/V projection: z selects (A, W, bias, C); z==2 stores V^T --
// Q output pre-scaled by 0.125*log2e (folds softmax scale AND exp->exp2).

struct QkvArgs { const u16* A[3]; const u16* W[3]; const float* bias[3]; u16* C[3]; };

__global__ __launch_bounds__(256, 2)
void gemm_qkv(QkvArgs args) {
  constexpr int CPAD = 136;
  __shared__ u16 smem[128 * CPAD];
  u16* lA = smem;
  u16* lB = smem + 8192;
  int tid = threadIdx.x, lane = tid & 63, w = tid >> 6;
  int wm = w & 1, wn = w >> 1;
  int sel = blockIdx.z;
  bool vt = (sel == 2);
  float scl = (sel == 0) ? 0.125f * LOG2E : 1.0f;
  long mBase = (long)blockIdx.y * 128;
  long nBase = (long)blockIdx.x * 128;
  const u16* Ab = args.A[sel] + mBase * (long)Dm;
  const u16* Bb = args.W[sel] + nBase * (long)Dm;
  const float* bias = args.bias[sel];
  u16* C = args.C[sel];

  floatx4 acc[4][4];
  #pragma unroll
  for (int i = 0; i < 4; ++i)
    #pragma unroll
    for (int j = 0; j < 4; ++j) acc[i][j] = floatx4{0.f, 0.f, 0.f, 0.f};

  for (int kt = 0; kt < Dm; kt += 64) {
    __syncthreads();
    stage_tile<128, 256>(Ab, Dm, kt, lA, tid);
    stage_tile<128, 256>(Bb, Dm, kt, lB, tid);
    __syncthreads();
    #pragma unroll
    for (int ks = 0; ks < 2; ++ks) {
      short8 af[4], bf[4];
      #pragma unroll
      for (int mi = 0; mi < 4; ++mi)
        af[mi] = read_frag(lA, wm*64 + mi*16 + (lane & 15), ks*4 + (lane >> 4));
      #pragma unroll
      for (int ni = 0; ni < 4; ++ni)
        bf[ni] = read_frag(lB, wn*64 + ni*16 + (lane & 15), ks*4 + (lane >> 4));
      #pragma unroll
      for (int mi = 0; mi < 4; ++mi)
        #pragma unroll
        for (int ni = 0; ni < 4; ++ni)
          acc[mi][ni] = mfma16(af[mi], bf[ni], acc[mi][ni]);
    }
  }

  __syncthreads();
  #pragma unroll
  for (int mi = 0; mi < 4; ++mi) {
    int rowb = wm*64 + mi*16 + ((lane >> 4) << 2);
    #pragma unroll
    for (int ni = 0; ni < 4; ++ni) {
      int col = wn*64 + ni*16 + (lane & 15);
      float bv = bias[nBase + col];
      #pragma unroll
      for (int r = 0; r < 4; ++r) {
        float v = (acc[mi][ni][r] + bv) * scl;
        if (!vt) smem[(rowb + r) * CPAD + col] = f2b(v);
        else     smem[col * CPAD + (rowb + r)] = f2b(v);
      }
    }
  }
  __syncthreads();
  #pragma unroll
  for (int i = 0; i < 8; ++i) {
    int idx = (i * 256 + tid) * 8;
    int r0 = idx >> 7, c0 = idx & 127;
    uint4 v = *(const uint4*)(smem + r0 * CPAD + c0);
    if (!vt) {
      *(uint4*)(C + (mBase + r0) * (long)Dm + nBase + c0) = v;
    } else {
      long m = mBase + c0;
      long ad = ((m >> 10) << 20) + ((nBase + r0) << 10) + (m & 1023);
      *(uint4*)(C + ad) = v;
    }
  }
}

// ---- generic BT GEMM: C[M,N] = A[M,K] @ B[N,K]^T (+bias) ----------------

constexpr int MO_BF16 = 0, MO_F32 = 1;

template<int BM, int BN, int WM, int WN, int MODE, bool BIAS, bool ZBH>
__global__ __launch_bounds__(WM*WN*64, 2)
void gemm_bt(const u16* __restrict__ A, const u16* __restrict__ Bmat,
             const float* __restrict__ bias, void* __restrict__ C,
             int K, int ldc) {
  constexpr int NT   = WM * WN * 64;
  constexpr int MI   = BM / WM / 16;
  constexpr int NI   = BN / WN / 16;
  constexpr int WROW = BM / WM;
  constexpr int WCOL = BN / WN;
  constexpr int STG  = (BM + BN) * 64;
  constexpr int CPAD = BN + 8;
  constexpr int CSZ  = BM * CPAD;
  constexpr int SM   = (MODE == MO_F32) ? STG : (STG > CSZ ? STG : CSZ);
  __shared__ u16 smem[SM];
  u16* lA = smem;
  u16* lB = smem + BM * 64;

  int tid = threadIdx.x, lane = tid & 63, w = tid >> 6;
  int wm = w % WM, wn = w / WM;
  long mBase = (long)blockIdx.y * BM;
  long nBase = (long)blockIdx.x * BN;
  long aOff = 0, bOff = 0, cOff = 0;
  if (ZBH) {
    int z = blockIdx.z, bz = z >> 4, h = z & 15;
    aOff = (long)h << 20;                 // att[h]
    bOff = (long)z << 16;                 // Vt[b][h]
    cOff = ((long)bz << 20) + h * HD;     // attv[b][q][h*64+d]
  }
  const u16* Ab = A + aOff + mBase * (long)K;
  const u16* Bb = Bmat + bOff + nBase * (long)K;

  floatx4 acc[MI][NI];
  #pragma unroll
  for (int i = 0; i < MI; ++i)
    #pragma unroll
    for (int j = 0; j < NI; ++j) acc[i][j] = floatx4{0.f, 0.f, 0.f, 0.f};

  for (int kt = 0; kt < K; kt += 64) {
    __syncthreads();
    stage_tile<BM, NT>(Ab, K, kt, lA, tid);
    stage_tile<BN, NT>(Bb, K, kt, lB, tid);
    __syncthreads();
    #pragma unroll
    for (int ks = 0; ks < 2; ++ks) {
      short8 af[MI], bf[NI];
      #pragma unroll
      for (int mi = 0; mi < MI; ++mi)
        af[mi] = read_frag(lA, wm*WROW + mi*16 + (lane & 15), ks*4 + (lane >> 4));
      #pragma unroll
      for (int ni = 0; ni < NI; ++ni)
        bf[ni] = read_frag(lB, wn*WCOL + ni*16 + (lane & 15), ks*4 + (lane >> 4));
      #pragma unroll
      for (int mi = 0; mi < MI; ++mi)
        #pragma unroll
        for (int ni = 0; ni < NI; ++ni)
          acc[mi][ni] = mfma16(af[mi], bf[ni], acc[mi][ni]);
    }
  }

  if (MODE == MO_F32) {
    #pragma unroll
    for (int mi = 0; mi < MI; ++mi) {
      int rowb = wm*WROW + mi*16 + ((lane >> 4) << 2);
      #pragma unroll
      for (int ni = 0; ni < NI; ++ni) {
        int col = wn*WCOL + ni*16 + (lane & 15);
        long n = nBase + col;
        float bv = BIAS ? bias[n] : 0.f;
        #pragma unroll
        for (int r = 0; r < 4; ++r)
          ((float*)C)[cOff + (mBase + rowb + r) * (long)ldc + n] = acc[mi][ni][r] + bv;
      }
    }
  } else {
    __syncthreads();
    #pragma unroll
    for (int mi = 0; mi < MI; ++mi) {
      int rowb = wm*WROW + mi*16 + ((lane >> 4) << 2);
      #pragma unroll
      for (int ni = 0; ni < NI; ++ni) {
        int col = wn*WCOL + ni*16 + (lane & 15);
        float bv = BIAS ? bias[nBase + col] : 0.f;
        #pragma unroll
        for (int r = 0; r < 4; ++r)
          smem[(rowb + r) * CPAD + col] = f2b(acc[mi][ni][r] + bv);
      }
    }
    __syncthreads();
    constexpr int TOT = BM * BN;
    #pragma unroll
    for (int i = 0; i < TOT / (NT * 8); ++i) {
      int idx = (i * NT + tid) * 8;
      int r0 = idx / BN, c0 = idx % BN;
      uint4 v = *(const uint4*)(smem + r0 * CPAD + c0);
      *(uint4*)((u16*)C + cOff + (mBase + r0) * (long)ldc + nBase + c0) = v;
    }
  }
}

// ---- pass A: l partial over a 256-wide k-chunk, ONE barrier --------------
// em uint4 loads hoisted BEFORE the barrier: they fly concurrently with the
// 48 KB staging drain instead of serializing after it (they don't touch LDS).
// grid (8,16,16): x=qT, y=h, z: b=z>>2, c=z&3.

__global__ __launch_bounds__(256)
void attn_stats(const u16* __restrict__ Q, const u16* __restrict__ Kw,
                const u16* __restrict__ emr4, float* __restrict__ lPart) {
  __shared__ u16 lQ[128 * 64];
  __shared__ u16 lK[2][128 * 64];
  int tid = threadIdx.x, lane = tid & 63, w = tid >> 6;
  int qT = blockIdx.x, h = blockIdx.y, z = blockIdx.z;
  int b = z >> 2, c = z & 3;
  const u16* Qb = Q + ((long)b << 20) + h * HD + (long)qT * 128 * Dm;
  const u16* Kb = Kw + ((long)b << 20) + h * HD + (long)c * 256 * Dm;

  stage_tile<128, 256>(Qb, Dm, 0, lQ, tid);
  stage_tile<128, 256>(Kb, Dm, 0, lK[0], tid);
  stage_tile<128, 256>(Kb + 128 * Dm, Dm, 0, lK[1], tid);

  // em prefetch into registers — overlaps the staging drain
  uint4 ev[2][2][4];
  #pragma unroll
  for (int kt = 0; kt < 2; ++kt) {
    int c2 = c * 2 + kt;
    #pragma unroll
    for (int mi = 0; mi < 2; ++mi) {
      int q4 = qT * 8 + w * 2 + mi;
      #pragma unroll
      for (int r = 0; r < 4; ++r) {
        long base = (((long)(q4 * 8 + c2) * 4 + r) << 9) + lane * 8;
        ev[kt][mi][r] = *(const uint4*)(emr4 + base);
      }
    }
  }
  __syncthreads();                       // the ONLY barrier

  short8 af[2][2];
  #pragma unroll
  for (int mi = 0; mi < 2; ++mi)
    #pragma unroll
    for (int ks = 0; ks < 2; ++ks)
      af[mi][ks] = read_frag(lQ, w*32 + mi*16 + (lane & 15), ks*4 + (lane >> 4));

  float lsum[2][4];
  #pragma unroll
  for (int mi = 0; mi < 2; ++mi)
    #pragma unroll
    for (int r = 0; r < 4; ++r) lsum[mi][r] = 0.f;

  #pragma unroll
  for (int kt = 0; kt < 2; ++kt) {
    const u16* lKc = lK[kt];
    floatx4 sc[2][8];
    #pragma unroll
    for (int mi = 0; mi < 2; ++mi)
      #pragma unroll
      for (int ni = 0; ni < 8; ++ni) sc[mi][ni] = floatx4{0.f, 0.f, 0.f, 0.f};
    #pragma unroll
    for (int ks = 0; ks < 2; ++ks) {
      short8 bf[8];
      #pragma unroll
      for (int ni = 0; ni < 8; ++ni)
        bf[ni] = read_frag(lKc, ni*16 + (lane & 15), ks*4 + (lane >> 4));
      #pragma unroll
      for (int mi = 0; mi < 2; ++mi)
        #pragma unroll
        for (int ni = 0; ni < 8; ++ni)
          sc[mi][ni] = mfma16(af[mi][ks], bf[ni], sc[mi][ni]);
    }
    #pragma unroll
    for (int mi = 0; mi < 2; ++mi)
      #pragma unroll
      for (int r = 0; r < 4; ++r) {
        const u16* e8 = (const u16*)&ev[kt][mi][r];
        float a = 0.f;
        #pragma unroll
        for (int ni = 0; ni < 8; ++ni)
          a += __builtin_amdgcn_exp2f(sc[mi][ni][r] + b2f(e8[ni]));
        lsum[mi][r] += a;
      }
  }
  // 16-lane butterfly sum per row
  #pragma unroll
  for (int mi = 0; mi < 2; ++mi)
    #pragma unroll
    for (int r = 0; r < 4; ++r) {
      float l = lsum[mi][r];
      #pragma unroll
      for (int off = 1; off < 16; off <<= 1) l += __shfl_xor(l, off);
      if ((lane & 15) == 0) {
        int q = qT*128 + w*32 + mi*16 + ((lane >> 4) << 2) + r;
        lPart[(long)c * 65536 + ((long)(b * 16 + h) << 10) + q] = l;
      }
    }
}

// ---- pass B: att[h,q,k] = (sum_b exp2(s'_b)/l_b) * em  (bf16 out) --------
// R7-verbatim (best-total config).

__global__ __launch_bounds__(256, 2)
void attn_probs(const u16* __restrict__ Q, const u16* __restrict__ Kw,
                const u16* __restrict__ em, const float* __restrict__ lPart,
                u16* __restrict__ att) {
  constexpr int CPAD = 136;
  __shared__ u16 smem[128 * CPAD];       // staging (16K elts) + output tile alias
  __shared__ float lL[128];
  u16* lQ = smem;
  u16* lK = smem + 8192;
  int tid = threadIdx.x, lane = tid & 63, w = tid >> 6;
  int wm = w & 1, wn = w >> 1;
  int kT = blockIdx.x, qT = blockIdx.y, h = blockIdx.z;
  long q0 = (long)qT * 128, k0 = (long)kT * 128;

  floatx4 pa[4][4];
  #pragma unroll
  for (int i = 0; i < 4; ++i)
    #pragma unroll
    for (int j = 0; j < 4; ++j) pa[i][j] = floatx4{0.f, 0.f, 0.f, 0.f};

  for (int b = 0; b < 4; ++b) {
    __syncthreads();
    stage_tile<128, 256>(Q + ((long)b << 20) + h * HD + q0 * Dm, Dm, 0, lQ, tid);
    stage_tile<128, 256>(Kw + ((long)b << 20) + h * HD + k0 * Dm, Dm, 0, lK, tid);
    if (tid < 128) {
      long base = ((long)(b * 16 + h) << 10) + q0 + tid;
      float l = 0.f;
      #pragma unroll
      for (int cch = 0; cch < 4; ++cch) l += lPart[(long)cch * 65536 + base];
      lL[tid] = (l > 0.f) ? 1.f / l : 0.f;   // dead row -> contributes 0
    }
    __syncthreads();
    floatx4 sc[4][4];
    #pragma unroll
    for (int i = 0; i < 4; ++i)
      #pragma unroll
      for (int j = 0; j < 4; ++j) sc[i][j] = floatx4{0.f, 0.f, 0.f, 0.f};
    #pragma unroll
    for (int ks = 0; ks < 2; ++ks) {
      short8 af[4], bf[4];
      #pragma unroll
      for (int mi = 0; mi < 4; ++mi)
        af[mi] = read_frag(lQ, wm*64 + mi*16 + (lane & 15), ks*4 + (lane >> 4));
      #pragma unroll
      for (int ni = 0; ni < 4; ++ni)
        bf[ni] = read_frag(lK, wn*64 + ni*16 + (lane & 15), ks*4 + (lane >> 4));
      #pragma unroll
      for (int mi = 0; mi < 4; ++mi)
        #pragma unroll
        for (int ni = 0; ni < 4; ++ni)
          sc[mi][ni] = mfma16(af[mi], bf[ni], sc[mi][ni]);
    }
    #pragma unroll
    for (int mi = 0; mi < 4; ++mi)
      #pragma unroll
      for (int r = 0; r < 4; ++r) {
        int qq = wm*64 + mi*16 + ((lane >> 4) << 2) + r;
        float li = lL[qq];
        #pragma unroll
        for (int ni = 0; ni < 4; ++ni)
          pa[mi][ni][r] += __builtin_amdgcn_exp2f(sc[mi][ni][r]) * li;
      }
  }

  // stage normalized p in LDS (row-major), coalesced store with em multiply
  __syncthreads();
  #pragma unroll
  for (int mi = 0; mi < 4; ++mi)
    #pragma unroll
    for (int ni = 0; ni < 4; ++ni) {
      int kc = wn*64 + ni*16 + (lane & 15);
      #pragma unroll
      for (int r = 0; r < 4; ++r) {
        int qq = wm*64 + mi*16 + ((lane >> 4) << 2) + r;
        smem[qq * CPAD + kc] = f2b(pa[mi][ni][r]);
      }
    }
  __syncthreads();
  #pragma unroll
  for (int i = 0; i < 8; ++i) {
    int idx = (i * 256 + tid) * 8;
    int r0 = idx >> 7, c0 = idx & 127;
    uint4 v  = *(const uint4*)(smem + r0 * CPAD + c0);
    uint4 ev = *(const uint4*)(em + (q0 + r0) * S_ + k0 + c0);
    const u16* pv = (const u16*)&v;
    const u16* ee = (const u16*)&ev;
    u16 ov[8];
    #pragma unroll
    for (int j = 0; j < 8; ++j) ov[j] = f2b(b2f(pv[j]) * b2f(ee[j]));
    *(uint4*)(att + ((long)h << 20) + (q0 + r0) * S_ + k0 + c0) = *(uint4*)ov;
  }
}

// ---- host ---------------------------------------------------------------

extern "C" void kernel_launch(void* const* d_in, const int* in_sizes, int n_in,
                              void* d_out, int out_size, void* d_ws, size_t ws_size,
                              hipStream_t stream) {
  const float* x    = (const float*)d_in[0];
  const float* y    = (const float*)d_in[1];
  const float* mask = (const float*)d_in[2];
  const float* Wq   = (const float*)d_in[3];
  const float* bq   = (const float*)d_in[4];
  const float* Wk   = (const float*)d_in[5];
  const float* bk   = (const float*)d_in[6];
  const float* Wv   = (const float*)d_in[7];
  const float* bv   = (const float*)d_in[8];
  const float* Wo   = (const float*)d_in[9];
  const float* bo   = (const float*)d_in[10];

  char* ws = (char*)d_ws;
  const long MB = 1024 * 1024;
  u16*  Qw   = (u16*)(ws + 0);            //  8 MB  (B,S,D) bf16, pre-scaled
  u16*  Kw   = (u16*)(ws + 8 * MB);       //  8 MB
  u16*  Vt   = (u16*)(ws + 16 * MB);      //  8 MB  (B,H,64,S) bf16 (V^T)
  u16*  attv = (u16*)(ws + 24 * MB);      //  8 MB  (B,S,D) bf16
  // lPart/em/emr4 overlay attv's region (consumed before AV GEMM writes attv)
  float* lPart = (float*)(ws + 24 * MB);  //  1 MB  [4 chunks][B,H,S]
  u16*  em   = (u16*)(ws + 25 * MB);      //  2 MB  exp(mask) bf16 (S,S)
  u16*  emr4 = (u16*)(ws + 27 * MB);      //  2 MB  mask*log2e bf16, emr4 layout
  u16*  Wob  = (u16*)(ws + 33 * MB);      //  2 MB
  u16*  att  = (u16*)(ws + 35 * MB);      // 32 MB  (H,S,S) bf16
  // transients overlaid inside att's region (consumed before att is written)
  u16*  yb   = (u16*)(ws + 35 * MB);      //  8 MB
  u16*  xb   = (u16*)(ws + 43 * MB);      //  8 MB
  u16*  Wqb  = (u16*)(ws + 51 * MB);      //  2 MB
  u16*  Wkb  = (u16*)(ws + 53 * MB);      //  2 MB
  u16*  Wvb  = (u16*)(ws + 55 * MB);      //  2 MB

  dim3 blk(256);
  CvtArgs ca;
  ca.s[0] = y;  ca.s[1] = x;  ca.s[2] = Wq;  ca.s[3] = Wk;  ca.s[4] = Wv;  ca.s[5] = Wo;
  ca.d[0] = yb; ca.d[1] = xb; ca.d[2] = Wqb; ca.d[3] = Wkb; ca.d[4] = Wvb; ca.d[5] = Wob;
  cvt_all<<<dim3(12288), blk, 0, stream>>>(ca);
  emask_prep<<<dim3(64), blk, 0, stream>>>(mask, em, emr4);

  QkvArgs qa;
  qa.A[0] = yb;  qa.A[1] = xb;  qa.A[2] = xb;
  qa.W[0] = Wqb; qa.W[1] = Wkb; qa.W[2] = Wvb;
  qa.bias[0] = bq; qa.bias[1] = bk; qa.bias[2] = bv;
  qa.C[0] = Qw;  qa.C[1] = Kw;  qa.C[2] = Vt;
  gemm_qkv<<<dim3(8, 32, 3), blk, 0, stream>>>(qa);

  attn_stats<<<dim3(8, 16, 16), blk, 0, stream>>>(Qw, Kw, emr4, lPart);
  attn_probs<<<dim3(8, 8, 16), blk, 0, stream>>>(Qw, Kw, em, lPart, att);

  // attv[b,q,h*64+d] = sum_k att[h,q,k] * Vt[b,h,d,k]   (512 blocks)
  gemm_bt<128,64,2,2,MO_BF16,false,true><<<dim3(1, 8, 64), blk, 0, stream>>>(att, Vt, nullptr, attv, 1024, 1024);
  // out = attv @ Wo^T + bo  (fp32, 512 blocks)
  gemm_bt<64,128,2,2,MO_F32,true,false><<<dim3(8, 64), blk, 0, stream>>>(attv, Wob, bo, d_out, 1024, 1024);
}

// Round 13
// 230.604 us; speedup vs baseline: 1.0835x; 1.0835x over previous
//
#include <hip/hip_runtime.h>

typedef unsigned short u16;
typedef unsigned int   u32;
typedef __attribute__((ext_vector_type(8))) short short8;   // 8 bf16 = 4 VGPRs
typedef __attribute__((ext_vector_type(4))) float floatx4;

#define DEV static __device__ __forceinline__

constexpr int S_  = 1024;   // sequence
constexpr int Dm  = 1024;   // d_model
constexpr int HD  = 64;     // head dim
constexpr float LOG2E = 1.44269504088896f;

// ---- helpers -------------------------------------------------------------

DEV u16 f2b(float f) {            // fp32 -> bf16, round-to-nearest-even
  u32 u = __builtin_bit_cast(u32, f);
  u = u + 0x7fffu + ((u >> 16) & 1u);
  return (u16)(u >> 16);
}
DEV float b2f(u16 h) { u32 u = ((u32)h) << 16; return __builtin_bit_cast(float, u); }

DEV void gld16(const u16* g, u16* l) {   // async global->LDS, 16B per lane
  __builtin_amdgcn_global_load_lds(
      (const __attribute__((address_space(1))) u32*)g,
      (__attribute__((address_space(3))) u32*)l, 16, 0, 0);
}

// Stage ROWS x 64 bf16 tile into LDS with XOR swizzle (16B block (m,kb) at
// m*8 + (kb ^ (m&7))) so ds_read_b128 fragment reads are 2-way (free, m136).
template<int ROWS, int NT>
DEV void stage_tile(const u16* src, long stride, long kOff, u16* lds, int tid) {
  constexpr int NBLK = ROWS * 8;
  constexpr int NISS = NBLK / NT;
  static_assert(NBLK % NT == 0, "");
  int w = tid >> 6;
  #pragma unroll
  for (int i = 0; i < NISS; ++i) {
    int bi = i * NT + tid;
    int m  = bi >> 3;
    int kb = (bi & 7) ^ (m & 7);
    const u16* g = src + (long)m * stride + kOff + (kb << 3);
    u16* l = lds + ((long)(i * NT + (w << 6)) << 3);   // wave-uniform chunk base
    gld16(g, l);
  }
}

// A/B fragment read: row = lane&15, kb = ks*4 + (lane>>4)
DEV short8 read_frag(const u16* lds, int m, int kb) {
  int off = (m << 6) + ((kb ^ (m & 7)) << 3);
  return *(const short8*)(lds + off);
}

DEV floatx4 mfma16(short8 a, short8 b, floatx4 c) {
  return __builtin_amdgcn_mfma_f32_16x16x32_bf16(a, b, c, 0, 0, 0);
}

// ---- fused fp32 -> bf16 convert (y, x, Wq, Wk, Wv, Wo) -------------------

struct CvtArgs { const float* s[6]; u16* d[6]; };

__global__ __launch_bounds__(256)
void cvt_all(CvtArgs a) {
  int b = blockIdx.x;
  int t, lb;
  if (b < 4096)      { t = 0; lb = b; }
  else if (b < 8192) { t = 1; lb = b - 4096; }
  else               { t = 2 + ((b - 8192) >> 10); lb = (b - 8192) & 1023; }
  int i = (lb * 256 + (int)threadIdx.x) * 4;
  float4 v = *(const float4*)(a.s[t] + i);
  u32 lo = (u32)f2b(v.x) | ((u32)f2b(v.y) << 16);
  u32 hi = (u32)f2b(v.z) | ((u32)f2b(v.w) << 16);
  uint2 o; o.x = lo; o.y = hi;
  *(uint2*)(a.d[t] + i) = o;
}

// ---- emask prep ----------------------------------------------------------
// em[q][k] = exp(mask[q][k]) bf16 row-major (probs epilogue).
// emr4[q4][c2][r][g][j][ii] = mask*log2e bf16 where q=q4*16+g*4+r,
// k=c2*128+ii*16+j.  In attn_stats one load instruction (fixed w,r,kt)
// reads a CONTIGUOUS 1 KB block across 64 lanes (16 lines, 100% utilized).

__global__ __launch_bounds__(256)
void emask_prep(const float* __restrict__ mask, u16* __restrict__ em,
                u16* __restrict__ emr4) {
  __shared__ u16 lp[16384];
  int tid = threadIdx.x;
  int q4 = blockIdx.x;                   // 64 blocks, 16 q-rows each
  #pragma unroll
  for (int rr = 0; rr < 16; ++rr) {
    long q = (long)q4 * 16 + rr;
    float4 v = *(const float4*)(mask + q * 1024 + tid * 4);
    u16 e0 = f2b(__expf(v.x)), e1 = f2b(__expf(v.y));
    u16 e2 = f2b(__expf(v.z)), e3 = f2b(__expf(v.w));
    uint2 o; o.x = (u32)e0 | ((u32)e1 << 16); o.y = (u32)e2 | ((u32)e3 << 16);
    *(uint2*)(em + q * 1024 + tid * 4) = o;
    int r = rr & 3, g = rr >> 2;
    float mv[4] = {v.x, v.y, v.z, v.w};
    #pragma unroll
    for (int j4 = 0; j4 < 4; ++j4) {
      int k = tid * 4 + j4;
      int c2 = k >> 7, ii = (k >> 4) & 7, j = k & 15;
      lp[((c2 * 4 + r) * 4 + g) * 128 + j * 8 + ii] = f2b(mv[j4] * LOG2E);
    }
  }
  __syncthreads();
  #pragma unroll
  for (int i = 0; i < 8; ++i) {
    int o = i * 2048 + tid * 8;
    *(uint4*)(emr4 + (long)q4 * 16384 + o) = *(const uint4*)(lp + o);
  }
}

// ---- fused Q/K/V projection: z selects (A, W, bias, C); z==2 stores V^T --
// Q output pre-scaled by 0.125*log2e (folds softmax scale AND exp->exp2).

struct QkvArgs { const u16* A[3]; const u16* W[3]; const float* bias[3]; u16* C[3]; };

__global__ __launch_bounds__(256, 2)
void gemm_qkv(QkvArgs args) {
  constexpr int CPAD = 136;
  __shared__ u16 smem[128 * CPAD];
  u16* lA = smem;
  u16* lB = smem + 8192;
  int tid = threadIdx.x, lane = tid & 63, w = tid >> 6;
  int wm = w & 1, wn = w >> 1;
  int sel = blockIdx.z;
  bool vt = (sel == 2);
  float scl = (sel == 0) ? 0.125f * LOG2E : 1.0f;
  long mBase = (long)blockIdx.y * 128;
  long nBase = (long)blockIdx.x * 128;
  const u16* Ab = args.A[sel] + mBase * (long)Dm;
  const u16* Bb = args.W[sel] + nBase * (long)Dm;
  const float* bias = args.bias[sel];
  u16* C = args.C[sel];

  floatx4 acc[4][4];
  #pragma unroll
  for (int i = 0; i < 4; ++i)
    #pragma unroll
    for (int j = 0; j < 4; ++j) acc[i][j] = floatx4{0.f, 0.f, 0.f, 0.f};

  for (int kt = 0; kt < Dm; kt += 64) {
    __syncthreads();
    stage_tile<128, 256>(Ab, Dm, kt, lA, tid);
    stage_tile<128, 256>(Bb, Dm, kt, lB, tid);
    __syncthreads();
    #pragma unroll
    for (int ks = 0; ks < 2; ++ks) {
      short8 af[4], bf[4];
      #pragma unroll
      for (int mi = 0; mi < 4; ++mi)
        af[mi] = read_frag(lA, wm*64 + mi*16 + (lane & 15), ks*4 + (lane >> 4));
      #pragma unroll
      for (int ni = 0; ni < 4; ++ni)
        bf[ni] = read_frag(lB, wn*64 + ni*16 + (lane & 15), ks*4 + (lane >> 4));
      #pragma unroll
      for (int mi = 0; mi < 4; ++mi)
        #pragma unroll
        for (int ni = 0; ni < 4; ++ni)
          acc[mi][ni] = mfma16(af[mi], bf[ni], acc[mi][ni]);
    }
  }

  __syncthreads();
  #pragma unroll
  for (int mi = 0; mi < 4; ++mi) {
    int rowb = wm*64 + mi*16 + ((lane >> 4) << 2);
    #pragma unroll
    for (int ni = 0; ni < 4; ++ni) {
      int col = wn*64 + ni*16 + (lane & 15);
      float bv = bias[nBase + col];
      #pragma unroll
      for (int r = 0; r < 4; ++r) {
        float v = (acc[mi][ni][r] + bv) * scl;
        if (!vt) smem[(rowb + r) * CPAD + col] = f2b(v);
        else     smem[col * CPAD + (rowb + r)] = f2b(v);
      }
    }
  }
  __syncthreads();
  #pragma unroll
  for (int i = 0; i < 8; ++i) {
    int idx = (i * 256 + tid) * 8;
    int r0 = idx >> 7, c0 = idx & 127;
    uint4 v = *(const uint4*)(smem + r0 * CPAD + c0);
    if (!vt) {
      *(uint4*)(C + (mBase + r0) * (long)Dm + nBase + c0) = v;
    } else {
      long m = mBase + c0;
      long ad = ((m >> 10) << 20) + ((nBase + r0) << 10) + (m & 1023);
      *(uint4*)(C + ad) = v;
    }
  }
}

// ---- generic BT GEMM: C[M,N] = A[M,K] @ B[N,K]^T (+bias) ----------------

constexpr int MO_BF16 = 0, MO_F32 = 1;

template<int BM, int BN, int WM, int WN, int MODE, bool BIAS, bool ZBH>
__global__ __launch_bounds__(WM*WN*64, 2)
void gemm_bt(const u16* __restrict__ A, const u16* __restrict__ Bmat,
             const float* __restrict__ bias, void* __restrict__ C,
             int K, int ldc) {
  constexpr int NT   = WM * WN * 64;
  constexpr int MI   = BM / WM / 16;
  constexpr int NI   = BN / WN / 16;
  constexpr int WROW = BM / WM;
  constexpr int WCOL = BN / WN;
  constexpr int STG  = (BM + BN) * 64;
  constexpr int CPAD = BN + 8;
  constexpr int CSZ  = BM * CPAD;
  constexpr int SM   = (MODE == MO_F32) ? STG : (STG > CSZ ? STG : CSZ);
  __shared__ u16 smem[SM];
  u16* lA = smem;
  u16* lB = smem + BM * 64;

  int tid = threadIdx.x, lane = tid & 63, w = tid >> 6;
  int wm = w % WM, wn = w / WM;
  long mBase = (long)blockIdx.y * BM;
  long nBase = (long)blockIdx.x * BN;
  long aOff = 0, bOff = 0, cOff = 0;
  if (ZBH) {
    int z = blockIdx.z, bz = z >> 4, h = z & 15;
    aOff = (long)h << 20;                 // att[h]
    bOff = (long)z << 16;                 // Vt[b][h]
    cOff = ((long)bz << 20) + h * HD;     // attv[b][q][h*64+d]
  }
  const u16* Ab = A + aOff + mBase * (long)K;
  const u16* Bb = Bmat + bOff + nBase * (long)K;

  floatx4 acc[MI][NI];
  #pragma unroll
  for (int i = 0; i < MI; ++i)
    #pragma unroll
    for (int j = 0; j < NI; ++j) acc[i][j] = floatx4{0.f, 0.f, 0.f, 0.f};

  for (int kt = 0; kt < K; kt += 64) {
    __syncthreads();
    stage_tile<BM, NT>(Ab, K, kt, lA, tid);
    stage_tile<BN, NT>(Bb, K, kt, lB, tid);
    __syncthreads();
    #pragma unroll
    for (int ks = 0; ks < 2; ++ks) {
      short8 af[MI], bf[NI];
      #pragma unroll
      for (int mi = 0; mi < MI; ++mi)
        af[mi] = read_frag(lA, wm*WROW + mi*16 + (lane & 15), ks*4 + (lane >> 4));
      #pragma unroll
      for (int ni = 0; ni < NI; ++ni)
        bf[ni] = read_frag(lB, wn*WCOL + ni*16 + (lane & 15), ks*4 + (lane >> 4));
      #pragma unroll
      for (int mi = 0; mi < MI; ++mi)
        #pragma unroll
        for (int ni = 0; ni < NI; ++ni)
          acc[mi][ni] = mfma16(af[mi], bf[ni], acc[mi][ni]);
    }
  }

  if (MODE == MO_F32) {
    #pragma unroll
    for (int mi = 0; mi < MI; ++mi) {
      int rowb = wm*WROW + mi*16 + ((lane >> 4) << 2);
      #pragma unroll
      for (int ni = 0; ni < NI; ++ni) {
        int col = wn*WCOL + ni*16 + (lane & 15);
        long n = nBase + col;
        float bv = BIAS ? bias[n] : 0.f;
        #pragma unroll
        for (int r = 0; r < 4; ++r)
          ((float*)C)[cOff + (mBase + rowb + r) * (long)ldc + n] = acc[mi][ni][r] + bv;
      }
    }
  } else {
    __syncthreads();
    #pragma unroll
    for (int mi = 0; mi < MI; ++mi) {
      int rowb = wm*WROW + mi*16 + ((lane >> 4) << 2);
      #pragma unroll
      for (int ni = 0; ni < NI; ++ni) {
        int col = wn*WCOL + ni*16 + (lane & 15);
        float bv = BIAS ? bias[nBase + col] : 0.f;
        #pragma unroll
        for (int r = 0; r < 4; ++r)
          smem[(rowb + r) * CPAD + col] = f2b(acc[mi][ni][r] + bv);
      }
    }
    __syncthreads();
    constexpr int TOT = BM * BN;
    #pragma unroll
    for (int i = 0; i < TOT / (NT * 8); ++i) {
      int idx = (i * NT + tid) * 8;
      int r0 = idx / BN, c0 = idx % BN;
      uint4 v = *(const uint4*)(smem + r0 * CPAD + c0);
      *(uint4*)((u16*)C + cOff + (mBase + r0) * (long)ldc + nBase + c0) = v;
    }
  }
}

// ---- pass A: l partial over a 256-wide k-chunk, ONE barrier, 8 WAVES -----
// 512-thread blocks: same 48 KB LDS and q-coverage (wave w owns 16 q rows),
// but 3 blocks/CU -> 24 waves/CU for latency hiding; per-wave staging issue
// halves. grid (8,16,16): x=qT, y=h, z: b=z>>2, c=z&3.

__global__ __launch_bounds__(512)
void attn_stats(const u16* __restrict__ Q, const u16* __restrict__ Kw,
                const u16* __restrict__ emr4, float* __restrict__ lPart) {
  __shared__ u16 lQ[128 * 64];
  __shared__ u16 lK[2][128 * 64];
  int tid = threadIdx.x, lane = tid & 63, w = tid >> 6;   // w in [0,8)
  int qT = blockIdx.x, h = blockIdx.y, z = blockIdx.z;
  int b = z >> 2, c = z & 3;
  const u16* Qb = Q + ((long)b << 20) + h * HD + (long)qT * 128 * Dm;
  const u16* Kb = Kw + ((long)b << 20) + h * HD + (long)c * 256 * Dm;

  stage_tile<128, 512>(Qb, Dm, 0, lQ, tid);
  stage_tile<128, 512>(Kb, Dm, 0, lK[0], tid);
  stage_tile<128, 512>(Kb + 128 * Dm, Dm, 0, lK[1], tid);
  __syncthreads();                       // the ONLY barrier

  short8 af[2];
  #pragma unroll
  for (int ks = 0; ks < 2; ++ks)
    af[ks] = read_frag(lQ, w*16 + (lane & 15), ks*4 + (lane >> 4));

  float lsum[4];
  #pragma unroll
  for (int r = 0; r < 4; ++r) lsum[r] = 0.f;

  int q4 = qT * 8 + w;                   // this wave's 16-row q group
  #pragma unroll
  for (int kt = 0; kt < 2; ++kt) {
    const u16* lKc = lK[kt];
    floatx4 sc[8];
    #pragma unroll
    for (int ni = 0; ni < 8; ++ni) sc[ni] = floatx4{0.f, 0.f, 0.f, 0.f};
    #pragma unroll
    for (int ks = 0; ks < 2; ++ks) {
      short8 bf[8];
      #pragma unroll
      for (int ni = 0; ni < 8; ++ni)
        bf[ni] = read_frag(lKc, ni*16 + (lane & 15), ks*4 + (lane >> 4));
      #pragma unroll
      for (int ni = 0; ni < 8; ++ni)
        sc[ni] = mfma16(af[ks], bf[ni], sc[ni]);
    }
    int c2 = c * 2 + kt;
    #pragma unroll
    for (int r = 0; r < 4; ++r) {
      long base = (((long)(q4 * 8 + c2) * 4 + r) << 9) + lane * 8;
      uint4 ev = *(const uint4*)(emr4 + base);
      const u16* e8 = (const u16*)&ev;
      float a = 0.f;
      #pragma unroll
      for (int ni = 0; ni < 8; ++ni)
        a += __builtin_amdgcn_exp2f(sc[ni][r] + b2f(e8[ni]));
      lsum[r] += a;
    }
  }
  // 16-lane butterfly sum per row
  #pragma unroll
  for (int r = 0; r < 4; ++r) {
    float l = lsum[r];
    #pragma unroll
    for (int off = 1; off < 16; off <<= 1) l += __shfl_xor(l, off);
    if ((lane & 15) == 0) {
      int q = qT*128 + w*16 + ((lane >> 4) << 2) + r;
      lPart[(long)c * 65536 + ((long)(b * 16 + h) << 10) + q] = l;
    }
  }
}

// ---- pass B: att[h,q,k] = (sum_b exp2(s'_b)/l_b) * em  (bf16 out) --------
// R7-verbatim (best-total config).

__global__ __launch_bounds__(256, 2)
void attn_probs(const u16* __restrict__ Q, const u16* __restrict__ Kw,
                const u16* __restrict__ em, const float* __restrict__ lPart,
                u16* __restrict__ att) {
  constexpr int CPAD = 136;
  __shared__ u16 smem[128 * CPAD];       // staging (16K elts) + output tile alias
  __shared__ float lL[128];
  u16* lQ = smem;
  u16* lK = smem + 8192;
  int tid = threadIdx.x, lane = tid & 63, w = tid >> 6;
  int wm = w & 1, wn = w >> 1;
  int kT = blockIdx.x, qT = blockIdx.y, h = blockIdx.z;
  long q0 = (long)qT * 128, k0 = (long)kT * 128;

  floatx4 pa[4][4];
  #pragma unroll
  for (int i = 0; i < 4; ++i)
    #pragma unroll
    for (int j = 0; j < 4; ++j) pa[i][j] = floatx4{0.f, 0.f, 0.f, 0.f};

  for (int b = 0; b < 4; ++b) {
    __syncthreads();
    stage_tile<128, 256>(Q + ((long)b << 20) + h * HD + q0 * Dm, Dm, 0, lQ, tid);
    stage_tile<128, 256>(Kw + ((long)b << 20) + h * HD + k0 * Dm, Dm, 0, lK, tid);
    if (tid < 128) {
      long base = ((long)(b * 16 + h) << 10) + q0 + tid;
      float l = 0.f;
      #pragma unroll
      for (int cch = 0; cch < 4; ++cch) l += lPart[(long)cch * 65536 + base];
      lL[tid] = (l > 0.f) ? 1.f / l : 0.f;   // dead row -> contributes 0
    }
    __syncthreads();
    floatx4 sc[4][4];
    #pragma unroll
    for (int i = 0; i < 4; ++i)
      #pragma unroll
      for (int j = 0; j < 4; ++j) sc[i][j] = floatx4{0.f, 0.f, 0.f, 0.f};
    #pragma unroll
    for (int ks = 0; ks < 2; ++ks) {
      short8 af[4], bf[4];
      #pragma unroll
      for (int mi = 0; mi < 4; ++mi)
        af[mi] = read_frag(lQ, wm*64 + mi*16 + (lane & 15), ks*4 + (lane >> 4));
      #pragma unroll
      for (int ni = 0; ni < 4; ++ni)
        bf[ni] = read_frag(lK, wn*64 + ni*16 + (lane & 15), ks*4 + (lane >> 4));
      #pragma unroll
      for (int mi = 0; mi < 4; ++mi)
        #pragma unroll
        for (int ni = 0; ni < 4; ++ni)
          sc[mi][ni] = mfma16(af[mi], bf[ni], sc[mi][ni]);
    }
    #pragma unroll
    for (int mi = 0; mi < 4; ++mi)
      #pragma unroll
      for (int r = 0; r < 4; ++r) {
        int qq = wm*64 + mi*16 + ((lane >> 4) << 2) + r;
        float li = lL[qq];
        #pragma unroll
        for (int ni = 0; ni < 4; ++ni)
          pa[mi][ni][r] += __builtin_amdgcn_exp2f(sc[mi][ni][r]) * li;
      }
  }

  // stage normalized p in LDS (row-major), coalesced store with em multiply
  __syncthreads();
  #pragma unroll
  for (int mi = 0; mi < 4; ++mi)
    #pragma unroll
    for (int ni = 0; ni < 4; ++ni) {
      int kc = wn*64 + ni*16 + (lane & 15);
      #pragma unroll
      for (int r = 0; r < 4; ++r) {
        int qq = wm*64 + mi*16 + ((lane >> 4) << 2) + r;
        smem[qq * CPAD + kc] = f2b(pa[mi][ni][r]);
      }
    }
  __syncthreads();
  #pragma unroll
  for (int i = 0; i < 8; ++i) {
    int idx = (i * 256 + tid) * 8;
    int r0 = idx >> 7, c0 = idx & 127;
    uint4 v  = *(const uint4*)(smem + r0 * CPAD + c0);
    uint4 ev = *(const uint4*)(em + (q0 + r0) * S_ + k0 + c0);
    const u16* pv = (const u16*)&v;
    const u16* ee = (const u16*)&ev;
    u16 ov[8];
    #pragma unroll
    for (int j = 0; j < 8; ++j) ov[j] = f2b(b2f(pv[j]) * b2f(ee[j]));
    *(uint4*)(att + ((long)h << 20) + (q0 + r0) * S_ + k0 + c0) = *(uint4*)ov;
  }
}

// ---- host ---------------------------------------------------------------

extern "C" void kernel_launch(void* const* d_in, const int* in_sizes, int n_in,
                              void* d_out, int out_size, void* d_ws, size_t ws_size,
                              hipStream_t stream) {
  const float* x    = (const float*)d_in[0];
  const float* y    = (const float*)d_in[1];
  const float* mask = (const float*)d_in[2];
  const float* Wq   = (const float*)d_in[3];
  const float* bq   = (const float*)d_in[4];
  const float* Wk   = (const float*)d_in[5];
  const float* bk   = (const float*)d_in[6];
  const float* Wv   = (const float*)d_in[7];
  const float* bv   = (const float*)d_in[8];
  const float* Wo   = (const float*)d_in[9];
  const float* bo   = (const float*)d_in[10];

  char* ws = (char*)d_ws;
  const long MB = 1024 * 1024;
  u16*  Qw   = (u16*)(ws + 0);            //  8 MB  (B,S,D) bf16, pre-scaled
  u16*  Kw   = (u16*)(ws + 8 * MB);       //  8 MB
  u16*  Vt   = (u16*)(ws + 16 * MB);      //  8 MB  (B,H,64,S) bf16 (V^T)
  u16*  attv = (u16*)(ws + 24 * MB);      //  8 MB  (B,S,D) bf16
  // lPart/em/emr4 overlay attv's region (consumed before AV GEMM writes attv)
  float* lPart = (float*)(ws + 24 * MB);  //  1 MB  [4 chunks][B,H,S]
  u16*  em   = (u16*)(ws + 25 * MB);      //  2 MB  exp(mask) bf16 (S,S)
  u16*  emr4 = (u16*)(ws + 27 * MB);      //  2 MB  mask*log2e bf16, emr4 layout
  u16*  Wob  = (u16*)(ws + 33 * MB);      //  2 MB
  u16*  att  = (u16*)(ws + 35 * MB);      // 32 MB  (H,S,S) bf16
  // transients overlaid inside att's region (consumed before att is written)
  u16*  yb   = (u16*)(ws + 35 * MB);      //  8 MB
  u16*  xb   = (u16*)(ws + 43 * MB);      //  8 MB
  u16*  Wqb  = (u16*)(ws + 51 * MB);      //  2 MB
  u16*  Wkb  = (u16*)(ws + 53 * MB);      //  2 MB
  u16*  Wvb  = (u16*)(ws + 55 * MB);      //  2 MB

  dim3 blk(256);
  CvtArgs ca;
  ca.s[0] = y;  ca.s[1] = x;  ca.s[2] = Wq;  ca.s[3] = Wk;  ca.s[4] = Wv;  ca.s[5] = Wo;
  ca.d[0] = yb; ca.d[1] = xb; ca.d[2] = Wqb; ca.d[3] = Wkb; ca.d[4] = Wvb; ca.d[5] = Wob;
  cvt_all<<<dim3(12288), blk, 0, stream>>>(ca);
  emask_prep<<<dim3(64), blk, 0, stream>>>(mask, em, emr4);

  QkvArgs qa;
  qa.A[0] = yb;  qa.A[1] = xb;  qa.A[2] = xb;
  qa.W[0] = Wqb; qa.W[1] = Wkb; qa.W[2] = Wvb;
  qa.bias[0] = bq; qa.bias[1] = bk; qa.bias[2] = bv;
  qa.C[0] = Qw;  qa.C[1] = Kw;  qa.C[2] = Vt;
  gemm_qkv<<<dim3(8, 32, 3), blk, 0, stream>>>(qa);

  attn_stats<<<dim3(8, 16, 16), dim3(512), 0, stream>>>(Qw, Kw, emr4, lPart);
  attn_probs<<<dim3(8, 8, 16), blk, 0, stream>>>(Qw, Kw, em, lPart, att);

  // attv[b,q,h*64+d] = sum_k att[h,q,k] * Vt[b,h,d,k]   (512 blocks)
  gemm_bt<128,64,2,2,MO_BF16,false,true><<<dim3(1, 8, 64), blk, 0, stream>>>(att, Vt, nullptr, attv, 1024, 1024);
  // out = attv @ Wo^T + bo  (fp32, 512 blocks)
  gemm_bt<64,128,2,2,MO_F32,true,false><<<dim3(8, 64), blk, 0, stream>>>(attv, Wob, bo, d_out, 1024, 1024);
}